// Round 14
// baseline (123.933 us; speedup 1.0000x reference)
//
#include <hip/hip_runtime.h>

typedef float f32x4 __attribute__((ext_vector_type(4)));
typedef float f32x16 __attribute__((ext_vector_type(16)));
typedef short short8 __attribute__((ext_vector_type(8)));
typedef short short4_t __attribute__((ext_vector_type(4)));

#define GLOAD_LDS16(gp, lp) \
  __builtin_amdgcn_global_load_lds((const __attribute__((address_space(1))) void*)(gp), \
                                   (__attribute__((address_space(3))) void*)(lp), 16, 0, 0)

__device__ __forceinline__ short f2bf(float f){
  unsigned u = __builtin_bit_cast(unsigned, f);
  u += 0x7fffu + ((u >> 16) & 1u);   // RNE, no NaN inputs here
  return (short)(u >> 16);
}

__device__ __forceinline__ float exp2_fast(float x){
  return __builtin_amdgcn_exp2f(x);  // v_exp_f32: 2^x
}

// ---------------- fused prep: x fp32->bf16, w_qkv/w_out transpose+cvt ----------------
__global__ __launch_bounds__(256) void prep_kernel(
    const float* __restrict__ x, const float* __restrict__ wqkv,
    const float* __restrict__ wout, short* __restrict__ xb,
    short* __restrict__ wqkvT, short* __restrict__ woutT)
{
  __shared__ float tile[32][33];
  const int bid = blockIdx.x, tid = threadIdx.x;
  if (bid < 512){
    int base = bid*2048 + tid;          // 2048 float4 per block
    #pragma unroll
    for (int it=0; it<8; it++){
      int i = base + it*256;
      f32x4 v = ((const f32x4*)x)[i];
      short4_t s;
      s[0]=f2bf(v[0]); s[1]=f2bf(v[1]); s[2]=f2bf(v[2]); s[3]=f2bf(v[3]);
      ((short4_t*)xb)[i] = s;
    }
    return;
  }
  const float* w; short* wT; int N, idx;
  if (bid < 3584){ w = wqkv; wT = wqkvT; N = 3072; idx = bid - 512;  }
  else           { w = wout; wT = woutT; N = 1024; idx = bid - 3584; }
  const int K = 1024;
  int bn = (idx % (N >> 5)) * 32, bk = (idx / (N >> 5)) * 32;
  int tx = tid & 31, ty = tid >> 5;
  #pragma unroll
  for (int r=ty; r<32; r+=8) tile[r][tx] = w[(size_t)(bk+r)*N + bn + tx];
  __syncthreads();
  #pragma unroll
  for (int r=ty; r<32; r+=8) wT[(size_t)(bn+r)*K + bk + tx] = f2bf(tile[tx][r]);
}

// ---------------- 128x128 bf16 GEMM: C = A[M][K] * Bt[N][K]^T ----------------
// MODE 0: fp32 C (no swizzle).  MODE 1: QKV epilogue -> q(prescaled,log2e)/k natural,
// V^T [bh][64][t] direct (cross-round ledger: scattered V^T stores are L3-absorbed).
// MODE 1 uses bijective XCD swizzle (T1): 768 blocks, nf = (flat%8)*96 + flat/8.
template<int MODE>
__global__ __launch_bounds__(256) void gemm128_kernel(
    const short* __restrict__ A, const short* __restrict__ Bt,
    float* __restrict__ Cf, short* __restrict__ qb_, short* __restrict__ kb_,
    short* __restrict__ vtb, int M, int N, int K)
{
  __shared__ short a_lds[128*64];
  __shared__ short b_lds[128*64];
  const int tid = threadIdx.x;
  const int lane = tid & 63;
  const int l15 = lane & 15, lg = lane >> 4;
  const int w  = tid >> 6;
  const int wr = w >> 1, wc = w & 1;
  int m0, n0;
  if (MODE == 1){
    int flat = blockIdx.y*32 + blockIdx.x;          // dispatch order (x fastest)
    int nf = (flat & 7)*96 + (flat >> 3);           // XCD gets contiguous chunk of 96
    m0 = (nf & 31) * 128; n0 = (nf >> 5) * 128;
  } else {
    m0 = blockIdx.x * 128; n0 = blockIdx.y * 128;
  }

  f32x4 acc[4][4];
  #pragma unroll
  for (int i=0;i<4;i++)
    #pragma unroll
    for (int j=0;j<4;j++) acc[i][j] = (f32x4){0.f,0.f,0.f,0.f};

  for (int kt = 0; kt < K; kt += 64){
    __syncthreads();
    #pragma unroll
    for (int i=0;i<4;i++){
      int u = i*256 + tid;
      int row = u >> 3, cu = u & 7;
      int kl = ((cu ^ (row & 7)) << 3);
      GLOAD_LDS16(A + (size_t)(m0+row)*K + kt + kl, a_lds + (size_t)(i*256 + (tid & ~63))*8);
    }
    #pragma unroll
    for (int i=0;i<4;i++){
      int u = i*256 + tid;
      int row = u >> 3, cu = u & 7;
      int kl = ((cu ^ (row & 7)) << 3);
      GLOAD_LDS16(Bt + (size_t)(n0+row)*K + kt + kl, b_lds + (size_t)(i*256 + (tid & ~63))*8);
    }
    asm volatile("s_waitcnt vmcnt(0)" ::: "memory");
    __syncthreads();

    #pragma unroll
    for (int kk=0;kk<2;kk++){
      short8 af[4], bfr[4];
      #pragma unroll
      for (int mi=0;mi<4;mi++){
        int row = wr*64 + mi*16 + l15;
        int uu = ((kk*4 + lg) ^ (row & 7));
        af[mi] = *(const short8*)&a_lds[row*64 + uu*8];
      }
      #pragma unroll
      for (int ni=0;ni<4;ni++){
        int row = wc*64 + ni*16 + l15;
        int uu = ((kk*4 + lg) ^ (row & 7));
        bfr[ni] = *(const short8*)&b_lds[row*64 + uu*8];
      }
      #pragma unroll
      for (int mi=0;mi<4;mi++)
        #pragma unroll
        for (int ni=0;ni<4;ni++)
          acc[mi][ni] = __builtin_amdgcn_mfma_f32_16x16x32_bf16(af[mi], bfr[ni], acc[mi][ni], 0,0,0);
    }
  }

  // epilogue: D layout col = lane&15, row = (lane>>4)*4 + r  [verified m89/m91]
  #pragma unroll
  for (int mi=0;mi<4;mi++){
    #pragma unroll
    for (int ni=0;ni<4;ni++){
      int col = n0 + wc*64 + ni*16 + l15;
      #pragma unroll
      for (int r=0;r<4;r++){
        int rowg = m0 + wr*64 + mi*16 + lg*4 + r;
        float v = acc[mi][ni][r];
        if (MODE == 0){
          Cf[(size_t)rowg*N + col] = v;
        } else {
          int three = col >> 10, hh = (col >> 6) & 15, e = col & 63;
          int bb = rowg >> 11, t = rowg & 2047;
          int bh = bb*16 + hh;
          // Q pre-scale: 1/sqrt(64) * log2(e)  (softmax computed in base 2)
          if (three == 0)      qb_[((size_t)bh*2048 + t)*64 + e] = f2bf(v * (0.125f*1.44269504f));
          else if (three == 1) kb_[((size_t)bh*2048 + t)*64 + e] = f2bf(v);
          else                 vtb[((size_t)bh*64 + e)*2048 + t] = f2bf(v);   // V^T direct
        }
      }
    }
  }
}

// ---------------- causal flash attention, 32x32 MFMA, P-in-register ----------------
// 256 threads = 4 waves, wave owns 32 q-rows (QBLK=128). KVBLK=128, dbuf, vmcnt(8).
__global__ __launch_bounds__(256) void attn_kernel(
    const short* __restrict__ q, const short* __restrict__ kbuf,
    const short* __restrict__ vt, short* __restrict__ ob)
{
  __shared__ short k_lds[2][128*64];      // [kv][k]
  __shared__ short v_lds[2][64*128];      // [d][kv] (V^T)

  const int tid = threadIdx.x, lane = tid & 63, w = tid >> 6;  // w 0..3
  const int l31 = lane & 31, hi = lane >> 5;
  const int qi = blockIdx.x >> 5;
  const int qb = (qi < 8) ? (15 - qi) : (qi - 8);   // paired blocks sum to 17 tiles
  const int bh = blockIdx.x & 31;
  const int q0 = qb * 128;

  const short* qg = q + ((size_t)bh*2048 + q0 + w*32 + l31)*64 + hi*8;
  short8 qf[4];
  #pragma unroll
  for (int kk=0;kk<4;kk++) qf[kk] = *(const short8*)(qg + kk*16);

  f32x16 o_acc[2];
  #pragma unroll
  for (int oc=0;oc<2;oc++)
    #pragma unroll
    for (int r=0;r<16;r++) o_acc[oc][r] = 0.f;
  float mreg = -1e30f, lreg = 0.f;

  const int sw = l31 & 7;
  int kro[4], vro[8];
  #pragma unroll
  for (int kk=0;kk<4;kk++) kro[kk] = l31*128 + (((kk*2+hi)^sw) << 4);
  #pragma unroll
  for (int ks=0;ks<8;ks++) vro[ks] = l31*256 + (((ks*2+hi)^sw) << 4);

  const int xk = ((tid & 7) ^ ((tid >> 3) & 7)) * 8;
  const int xv = ((tid & 15) ^ ((tid >> 4) & 7)) * 8;
  const short* kp = kbuf + (size_t)bh*2048*64 + (size_t)(tid >> 3)*64 + xk;
  const short* vp = vt   + (size_t)bh*64*2048 + (size_t)(tid >> 4)*2048 + xv;
  const int dst = (tid & ~63)*8;

  const int n = qb + 1;
  #pragma unroll
  for (int i=0;i<4;i++) GLOAD_LDS16(kp + i*2048,  &k_lds[0][i*2048 + dst]);
  #pragma unroll
  for (int i=0;i<4;i++) GLOAD_LDS16(vp + i*32768, &v_lds[0][i*2048 + dst]);
  kp += 8192; vp += 128;

  for (int s = 0; s < n; s++){
    const int cur = s & 1;
    if (s + 1 < n){
      #pragma unroll
      for (int i=0;i<4;i++) GLOAD_LDS16(kp + i*2048,  &k_lds[cur^1][i*2048 + dst]);
      #pragma unroll
      for (int i=0;i<4;i++) GLOAD_LDS16(vp + i*32768, &v_lds[cur^1][i*2048 + dst]);
      kp += 8192; vp += 128;
      asm volatile("s_waitcnt vmcnt(8)" ::: "memory");
    } else {
      asm volatile("s_waitcnt vmcnt(0)" ::: "memory");
    }
    __builtin_amdgcn_s_barrier();

    const char* kl_ = (const char*)&k_lds[cur][0];
    const char* vl_ = (const char*)&v_lds[cur][0];

    f32x16 sacc[4];
    #pragma unroll
    for (int ct=0;ct<4;ct++)
      #pragma unroll
      for (int r=0;r<16;r++) sacc[ct][r] = 0.f;
    __builtin_amdgcn_s_setprio(1);
    #pragma unroll
    for (int kk=0;kk<4;kk++){
      #pragma unroll
      for (int ct=0;ct<4;ct++){
        short8 kf = *(const short8*)(kl_ + kro[kk] + ct*4096);
        sacc[ct] = __builtin_amdgcn_mfma_f32_32x32x16_bf16(kf, qf[kk], sacc[ct], 0,0,0);
      }
    }
    __builtin_amdgcn_s_setprio(0);

    if (s == qb){
      const int qloc = w*32 + l31 - 4*hi;
      #pragma unroll
      for (int ct=0;ct<4;ct++)
        #pragma unroll
        for (int r=0;r<16;r++)
          if (ct*32 + (r&3) + 8*(r>>2) > qloc) sacc[ct][r] = -1e30f;
    }

    float pmax = sacc[0][0];
    #pragma unroll
    for (int ct=0;ct<4;ct++)
      #pragma unroll
      for (int r=0;r<16;r++) pmax = fmaxf(pmax, sacc[ct][r]);
    pmax = fmaxf(pmax, __shfl_xor(pmax, 32));

    if (!__all(pmax - mreg <= 8.0f)){       // T13 defer-rescale
      float mnew = fmaxf(mreg, pmax);
      float alpha = exp2_fast(mreg - mnew);
      mreg = mnew;
      lreg *= alpha;
      float aRow[16];
      #pragma unroll
      for (int r=0;r<16;r++) aRow[r] = __shfl(alpha, (r&3) + 8*(r>>2) + 4*hi);
      #pragma unroll
      for (int oc=0;oc<2;oc++)
        #pragma unroll
        for (int r=0;r<16;r++) o_acc[oc][r] *= aRow[r];
    }

    float sum = 0.f;
    #pragma unroll
    for (int ct=0;ct<4;ct++){
      float pv[16];
      #pragma unroll
      for (int r=0;r<16;r++){ pv[r] = exp2_fast(sacc[ct][r] - mreg); sum += pv[r]; }
      unsigned pk[8];
      #pragma unroll
      for (int t=0;t<8;t++)
        asm("v_cvt_pk_bf16_f32 %0, %1, %2" : "=v"(pk[t]) : "v"(pv[2*t]), "v"(pv[2*t+1]));
      #pragma unroll
      for (int kss=0;kss<2;kss++){
        const int W = 4*kss;
        unsigned x0 = pk[W],   x2 = pk[W+2];
        unsigned x1 = pk[W+1], x3 = pk[W+3];
        asm("v_permlane32_swap_b32 %0, %1" : "+v"(x0), "+v"(x2));
        asm("v_permlane32_swap_b32 %0, %1" : "+v"(x1), "+v"(x3));
        uint4 pau = {x0, x1, x2, x3};
        short8 pa = __builtin_bit_cast(short8, pau);
        __builtin_amdgcn_s_setprio(1);
        #pragma unroll
        for (int oc=0;oc<2;oc++){
          short8 vf = *(const short8*)(vl_ + vro[2*ct+kss] + oc*8192);
          o_acc[oc] = __builtin_amdgcn_mfma_f32_32x32x16_bf16(pa, vf, o_acc[oc], 0,0,0);
        }
        __builtin_amdgcn_s_setprio(0);
      }
    }
    sum += __shfl_xor(sum, 32);
    lreg += sum;

    __builtin_amdgcn_s_barrier();
  }

  const int bb = bh >> 4, hh = bh & 15;
  #pragma unroll
  for (int r=0;r<16;r++){
    float lf = __shfl(lreg, (r&3) + 8*(r>>2) + 4*hi);
    float inv = 1.0f / lf;
    int t = q0 + w*32 + (r&3) + 8*(r>>2) + 4*hi;
    size_t base = ((size_t)(bb*2048 + t))*1024 + (size_t)hh*64 + l31;
    ob[base]      = f2bf(o_acc[0][r] * inv);
    ob[base + 32] = f2bf(o_acc[1][r] * inv);
  }
}

extern "C" void kernel_launch(void* const* d_in, const int* in_sizes, int n_in,
                              void* d_out, int out_size, void* d_ws, size_t ws_size,
                              hipStream_t stream) {
  const float* x     = (const float*)d_in[0];   // [2,2048,1024]
  const float* w_qkv = (const float*)d_in[1];   // [1024,3072]
  const float* w_out = (const float*)d_in[2];   // [1024,1024]
  float* out = (float*)d_out;                   // [2,2048,1024] fp32

  char* ws = (char*)d_ws;
  short* xb    = (short*)(ws);                    // 8 MB  [4096][1024] bf16
  short* wqkvT = (short*)(ws + (8u  << 20));      // 6 MB  [3072][1024] bf16
  short* woutT = (short*)(ws + (14u << 20));      // 2 MB  [1024][1024] bf16
  short* qbuf  = (short*)(ws + (16u << 20));      // 8 MB  [32][2048][64] bf16 (prescaled)
  short* kbuf  = (short*)(ws + (24u << 20));      // 8 MB  [32][2048][64] bf16
  short* vtbuf = (short*)(ws + (32u << 20));      // 8 MB  [32][64][2048] bf16 (V^T)
  short* obuf  = (short*)(ws + (40u << 20));      // 8 MB  [4096][1024] bf16

  prep_kernel<<<4608, 256, 0, stream>>>(x, w_qkv, w_out, xb, wqkvT, woutT);
  gemm128_kernel<1><<<dim3(32,24), 256, 0, stream>>>(xb, wqkvT, nullptr,
                                                     qbuf, kbuf, vtbuf, 4096, 3072, 1024);
  attn_kernel<<<dim3(512), 256, 0, stream>>>(qbuf, kbuf, vtbuf, obuf);
  gemm128_kernel<0><<<dim3(32,8), 256, 0, stream>>>(obuf, woutT, out,
                                                    nullptr, nullptr, nullptr, 4096, 1024, 1024);
}

// Round 17
// 112.878 us; speedup vs baseline: 1.0979x; 1.0979x over previous
//
#include <hip/hip_runtime.h>

typedef float f32x4 __attribute__((ext_vector_type(4)));
typedef float f32x16 __attribute__((ext_vector_type(16)));
typedef short short8 __attribute__((ext_vector_type(8)));
typedef short short4_t __attribute__((ext_vector_type(4)));

#define GLOAD_LDS16(gp, lp) \
  __builtin_amdgcn_global_load_lds((const __attribute__((address_space(1))) void*)(gp), \
                                   (__attribute__((address_space(3))) void*)(lp), 16, 0, 0)

__device__ __forceinline__ short f2bf(float f){
  unsigned u = __builtin_bit_cast(unsigned, f);
  u += 0x7fffu + ((u >> 16) & 1u);   // RNE, no NaN inputs here
  return (short)(u >> 16);
}

__device__ __forceinline__ float exp2_fast(float x){
  return __builtin_amdgcn_exp2f(x);  // v_exp_f32: 2^x
}

// ---------------- fused prep: x fp32->bf16, w_qkv/w_out transpose+cvt ----------------
__global__ __launch_bounds__(256) void prep_kernel(
    const float* __restrict__ x, const float* __restrict__ wqkv,
    const float* __restrict__ wout, short* __restrict__ xb,
    short* __restrict__ wqkvT, short* __restrict__ woutT)
{
  __shared__ float tile[32][33];
  const int bid = blockIdx.x, tid = threadIdx.x;
  if (bid < 512){
    int base = bid*2048 + tid;          // 2048 float4 per block
    #pragma unroll
    for (int it=0; it<8; it++){
      int i = base + it*256;
      f32x4 v = ((const f32x4*)x)[i];
      short4_t s;
      s[0]=f2bf(v[0]); s[1]=f2bf(v[1]); s[2]=f2bf(v[2]); s[3]=f2bf(v[3]);
      ((short4_t*)xb)[i] = s;
    }
    return;
  }
  const float* w; short* wT; int N, idx;
  if (bid < 3584){ w = wqkv; wT = wqkvT; N = 3072; idx = bid - 512;  }
  else           { w = wout; wT = woutT; N = 1024; idx = bid - 3584; }
  const int K = 1024;
  int bn = (idx % (N >> 5)) * 32, bk = (idx / (N >> 5)) * 32;
  int tx = tid & 31, ty = tid >> 5;
  #pragma unroll
  for (int r=ty; r<32; r+=8) tile[r][tx] = w[(size_t)(bk+r)*N + bn + tx];
  __syncthreads();
  #pragma unroll
  for (int r=ty; r<32; r+=8) wT[(size_t)(bn+r)*K + bk + tx] = f2bf(tile[tx][r]);
}

// ---------------- 128x128 bf16 GEMM: C = A[M][K] * Bt[N][K]^T ----------------
// MODE 0: fp32 C.  MODE 1: QKV epilogue -> q(prescaled,log2e)/k natural [bh][t][64],
// V^T [bh][64][t] direct (scattered 2B stores are L2/L3-absorbed; WRITE_SIZE showed
// no amplification in round-14 counters). NO XCD swizzle: default dispatch order
// (m fastest) already keeps the n-band shared chip-wide; round-14's chunked swizzle
// made every XCD stream full A (FETCH 36.7MB vs ~14 ideal) and cost 12us.
template<int MODE>
__global__ __launch_bounds__(256) void gemm128_kernel(
    const short* __restrict__ A, const short* __restrict__ Bt,
    float* __restrict__ Cf, short* __restrict__ qb_, short* __restrict__ kb_,
    short* __restrict__ vtb, int M, int N, int K)
{
  __shared__ short a_lds[128*64];
  __shared__ short b_lds[128*64];
  const int tid = threadIdx.x;
  const int lane = tid & 63;
  const int l15 = lane & 15, lg = lane >> 4;
  const int w  = tid >> 6;
  const int wr = w >> 1, wc = w & 1;
  const int m0 = blockIdx.x * 128, n0 = blockIdx.y * 128;

  f32x4 acc[4][4];
  #pragma unroll
  for (int i=0;i<4;i++)
    #pragma unroll
    for (int j=0;j<4;j++) acc[i][j] = (f32x4){0.f,0.f,0.f,0.f};

  for (int kt = 0; kt < K; kt += 64){
    __syncthreads();
    #pragma unroll
    for (int i=0;i<4;i++){
      int u = i*256 + tid;
      int row = u >> 3, cu = u & 7;
      int kl = ((cu ^ (row & 7)) << 3);
      GLOAD_LDS16(A + (size_t)(m0+row)*K + kt + kl, a_lds + (size_t)(i*256 + (tid & ~63))*8);
    }
    #pragma unroll
    for (int i=0;i<4;i++){
      int u = i*256 + tid;
      int row = u >> 3, cu = u & 7;
      int kl = ((cu ^ (row & 7)) << 3);
      GLOAD_LDS16(Bt + (size_t)(n0+row)*K + kt + kl, b_lds + (size_t)(i*256 + (tid & ~63))*8);
    }
    asm volatile("s_waitcnt vmcnt(0)" ::: "memory");
    __syncthreads();

    #pragma unroll
    for (int kk=0;kk<2;kk++){
      short8 af[4], bfr[4];
      #pragma unroll
      for (int mi=0;mi<4;mi++){
        int row = wr*64 + mi*16 + l15;
        int uu = ((kk*4 + lg) ^ (row & 7));
        af[mi] = *(const short8*)&a_lds[row*64 + uu*8];
      }
      #pragma unroll
      for (int ni=0;ni<4;ni++){
        int row = wc*64 + ni*16 + l15;
        int uu = ((kk*4 + lg) ^ (row & 7));
        bfr[ni] = *(const short8*)&b_lds[row*64 + uu*8];
      }
      #pragma unroll
      for (int mi=0;mi<4;mi++)
        #pragma unroll
        for (int ni=0;ni<4;ni++)
          acc[mi][ni] = __builtin_amdgcn_mfma_f32_16x16x32_bf16(af[mi], bfr[ni], acc[mi][ni], 0,0,0);
    }
  }

  // epilogue: D layout col = lane&15, row = (lane>>4)*4 + r  [verified m89/m91]
  #pragma unroll
  for (int mi=0;mi<4;mi++){
    #pragma unroll
    for (int ni=0;ni<4;ni++){
      int col = n0 + wc*64 + ni*16 + l15;
      #pragma unroll
      for (int r=0;r<4;r++){
        int rowg = m0 + wr*64 + mi*16 + lg*4 + r;
        float v = acc[mi][ni][r];
        if (MODE == 0){
          Cf[(size_t)rowg*N + col] = v;
        } else {
          int three = col >> 10, hh = (col >> 6) & 15, e = col & 63;
          int bb = rowg >> 11, t = rowg & 2047;
          int bh = bb*16 + hh;
          // Q pre-scale: 1/sqrt(64) * log2(e)  (softmax computed in base 2)
          if (three == 0)      qb_[((size_t)bh*2048 + t)*64 + e] = f2bf(v * (0.125f*1.44269504f));
          else if (three == 1) kb_[((size_t)bh*2048 + t)*64 + e] = f2bf(v);
          else                 vtb[((size_t)bh*64 + e)*2048 + t] = f2bf(v);   // V^T direct
        }
      }
    }
  }
}

// ---------------- causal flash attention, 32x32 MFMA, P-in-register ----------------
// 256 threads = 4 waves, wave owns 32 q-rows (QBLK=128). KVBLK=128, dbuf, vmcnt(8).
__global__ __launch_bounds__(256) void attn_kernel(
    const short* __restrict__ q, const short* __restrict__ kbuf,
    const short* __restrict__ vt, short* __restrict__ ob)
{
  __shared__ short k_lds[2][128*64];      // [kv][k]
  __shared__ short v_lds[2][64*128];      // [d][kv] (V^T)

  const int tid = threadIdx.x, lane = tid & 63, w = tid >> 6;  // w 0..3
  const int l31 = lane & 31, hi = lane >> 5;
  const int qi = blockIdx.x >> 5;
  const int qb = (qi < 8) ? (15 - qi) : (qi - 8);   // paired blocks sum to 17 tiles
  const int bh = blockIdx.x & 31;
  const int q0 = qb * 128;

  const short* qg = q + ((size_t)bh*2048 + q0 + w*32 + l31)*64 + hi*8;
  short8 qf[4];
  #pragma unroll
  for (int kk=0;kk<4;kk++) qf[kk] = *(const short8*)(qg + kk*16);

  f32x16 o_acc[2];
  #pragma unroll
  for (int oc=0;oc<2;oc++)
    #pragma unroll
    for (int r=0;r<16;r++) o_acc[oc][r] = 0.f;
  float mreg = -1e30f, lreg = 0.f;

  const int sw = l31 & 7;
  int kro[4], vro[8];
  #pragma unroll
  for (int kk=0;kk<4;kk++) kro[kk] = l31*128 + (((kk*2+hi)^sw) << 4);
  #pragma unroll
  for (int ks=0;ks<8;ks++) vro[ks] = l31*256 + (((ks*2+hi)^sw) << 4);

  const int xk = ((tid & 7) ^ ((tid >> 3) & 7)) * 8;
  const int xv = ((tid & 15) ^ ((tid >> 4) & 7)) * 8;
  const short* kp = kbuf + (size_t)bh*2048*64 + (size_t)(tid >> 3)*64 + xk;
  const short* vp = vt   + (size_t)bh*64*2048 + (size_t)(tid >> 4)*2048 + xv;
  const int dst = (tid & ~63)*8;

  const int n = qb + 1;
  #pragma unroll
  for (int i=0;i<4;i++) GLOAD_LDS16(kp + i*2048,  &k_lds[0][i*2048 + dst]);
  #pragma unroll
  for (int i=0;i<4;i++) GLOAD_LDS16(vp + i*32768, &v_lds[0][i*2048 + dst]);
  kp += 8192; vp += 128;

  for (int s = 0; s < n; s++){
    const int cur = s & 1;
    if (s + 1 < n){
      #pragma unroll
      for (int i=0;i<4;i++) GLOAD_LDS16(kp + i*2048,  &k_lds[cur^1][i*2048 + dst]);
      #pragma unroll
      for (int i=0;i<4;i++) GLOAD_LDS16(vp + i*32768, &v_lds[cur^1][i*2048 + dst]);
      kp += 8192; vp += 128;
      asm volatile("s_waitcnt vmcnt(8)" ::: "memory");
    } else {
      asm volatile("s_waitcnt vmcnt(0)" ::: "memory");
    }
    __builtin_amdgcn_s_barrier();

    const char* kl_ = (const char*)&k_lds[cur][0];
    const char* vl_ = (const char*)&v_lds[cur][0];

    f32x16 sacc[4];
    #pragma unroll
    for (int ct=0;ct<4;ct++)
      #pragma unroll
      for (int r=0;r<16;r++) sacc[ct][r] = 0.f;
    __builtin_amdgcn_s_setprio(1);
    #pragma unroll
    for (int kk=0;kk<4;kk++){
      #pragma unroll
      for (int ct=0;ct<4;ct++){
        short8 kf = *(const short8*)(kl_ + kro[kk] + ct*4096);
        sacc[ct] = __builtin_amdgcn_mfma_f32_32x32x16_bf16(kf, qf[kk], sacc[ct], 0,0,0);
      }
    }
    __builtin_amdgcn_s_setprio(0);

    if (s == qb){
      const int qloc = w*32 + l31 - 4*hi;
      #pragma unroll
      for (int ct=0;ct<4;ct++)
        #pragma unroll
        for (int r=0;r<16;r++)
          if (ct*32 + (r&3) + 8*(r>>2) > qloc) sacc[ct][r] = -1e30f;
    }

    float pmax = sacc[0][0];
    #pragma unroll
    for (int ct=0;ct<4;ct++)
      #pragma unroll
      for (int r=0;r<16;r++) pmax = fmaxf(pmax, sacc[ct][r]);
    pmax = fmaxf(pmax, __shfl_xor(pmax, 32));

    if (!__all(pmax - mreg <= 8.0f)){       // T13 defer-rescale
      float mnew = fmaxf(mreg, pmax);
      float alpha = exp2_fast(mreg - mnew);
      mreg = mnew;
      lreg *= alpha;
      float aRow[16];
      #pragma unroll
      for (int r=0;r<16;r++) aRow[r] = __shfl(alpha, (r&3) + 8*(r>>2) + 4*hi);
      #pragma unroll
      for (int oc=0;oc<2;oc++)
        #pragma unroll
        for (int r=0;r<16;r++) o_acc[oc][r] *= aRow[r];
    }

    float sum = 0.f;
    #pragma unroll
    for (int ct=0;ct<4;ct++){
      float pv[16];
      #pragma unroll
      for (int r=0;r<16;r++){ pv[r] = exp2_fast(sacc[ct][r] - mreg); sum += pv[r]; }
      unsigned pk[8];
      #pragma unroll
      for (int t=0;t<8;t++)
        asm("v_cvt_pk_bf16_f32 %0, %1, %2" : "=v"(pk[t]) : "v"(pv[2*t]), "v"(pv[2*t+1]));
      #pragma unroll
      for (int kss=0;kss<2;kss++){
        const int W = 4*kss;
        unsigned x0 = pk[W],   x2 = pk[W+2];
        unsigned x1 = pk[W+1], x3 = pk[W+3];
        asm("v_permlane32_swap_b32 %0, %1" : "+v"(x0), "+v"(x2));
        asm("v_permlane32_swap_b32 %0, %1" : "+v"(x1), "+v"(x3));
        uint4 pau = {x0, x1, x2, x3};
        short8 pa = __builtin_bit_cast(short8, pau);
        __builtin_amdgcn_s_setprio(1);
        #pragma unroll
        for (int oc=0;oc<2;oc++){
          short8 vf = *(const short8*)(vl_ + vro[2*ct+kss] + oc*8192);
          o_acc[oc] = __builtin_amdgcn_mfma_f32_32x32x16_bf16(pa, vf, o_acc[oc], 0,0,0);
        }
        __builtin_amdgcn_s_setprio(0);
      }
    }
    sum += __shfl_xor(sum, 32);
    lreg += sum;

    __builtin_amdgcn_s_barrier();
  }

  const int bb = bh >> 4, hh = bh & 15;
  #pragma unroll
  for (int r=0;r<16;r++){
    float lf = __shfl(lreg, (r&3) + 8*(r>>2) + 4*hi);
    float inv = 1.0f / lf;
    int t = q0 + w*32 + (r&3) + 8*(r>>2) + 4*hi;
    size_t base = ((size_t)(bb*2048 + t))*1024 + (size_t)hh*64 + l31;
    ob[base]      = f2bf(o_acc[0][r] * inv);
    ob[base + 32] = f2bf(o_acc[1][r] * inv);
  }
}

extern "C" void kernel_launch(void* const* d_in, const int* in_sizes, int n_in,
                              void* d_out, int out_size, void* d_ws, size_t ws_size,
                              hipStream_t stream) {
  const float* x     = (const float*)d_in[0];   // [2,2048,1024]
  const float* w_qkv = (const float*)d_in[1];   // [1024,3072]
  const float* w_out = (const float*)d_in[2];   // [1024,1024]
  float* out = (float*)d_out;                   // [2,2048,1024] fp32

  char* ws = (char*)d_ws;
  short* xb    = (short*)(ws);                    // 8 MB  [4096][1024] bf16
  short* wqkvT = (short*)(ws + (8u  << 20));      // 6 MB  [3072][1024] bf16
  short* woutT = (short*)(ws + (14u << 20));      // 2 MB  [1024][1024] bf16
  short* qbuf  = (short*)(ws + (16u << 20));      // 8 MB  [32][2048][64] bf16 (prescaled)
  short* kbuf  = (short*)(ws + (24u << 20));      // 8 MB  [32][2048][64] bf16
  short* vtbuf = (short*)(ws + (32u << 20));      // 8 MB  [32][64][2048] bf16 (V^T)
  short* obuf  = (short*)(ws + (40u << 20));      // 8 MB  [4096][1024] bf16

  prep_kernel<<<4608, 256, 0, stream>>>(x, w_qkv, w_out, xb, wqkvT, woutT);
  gemm128_kernel<1><<<dim3(32,24), 256, 0, stream>>>(xb, wqkvT, nullptr,
                                                     qbuf, kbuf, vtbuf, 4096, 3072, 1024);
  attn_kernel<<<dim3(512), 256, 0, stream>>>(qbuf, kbuf, vtbuf, obuf);
  gemm128_kernel<0><<<dim3(32,8), 256, 0, stream>>>(obuf, woutT, out,
                                                    nullptr, nullptr, nullptr, 4096, 1024, 1024);
}

// Round 18
// 103.594 us; speedup vs baseline: 1.1963x; 1.0896x over previous
//
#include <hip/hip_runtime.h>

typedef float f32x4 __attribute__((ext_vector_type(4)));
typedef float f32x16 __attribute__((ext_vector_type(16)));
typedef short short8 __attribute__((ext_vector_type(8)));
typedef short short4_t __attribute__((ext_vector_type(4)));

#define GLOAD_LDS16(gp, lp) \
  __builtin_amdgcn_global_load_lds((const __attribute__((address_space(1))) void*)(gp), \
                                   (__attribute__((address_space(3))) void*)(lp), 16, 0, 0)

__device__ __forceinline__ short f2bf(float f){
  unsigned u = __builtin_bit_cast(unsigned, f);
  u += 0x7fffu + ((u >> 16) & 1u);   // RNE, no NaN inputs here
  return (short)(u >> 16);
}

__device__ __forceinline__ float exp2_fast(float x){
  return __builtin_amdgcn_exp2f(x);  // v_exp_f32: 2^x
}

// ---------------- fused prep: x fp32->bf16, w_qkv/w_out transpose+cvt ----------------
__global__ __launch_bounds__(256) void prep_kernel(
    const float* __restrict__ x, const float* __restrict__ wqkv,
    const float* __restrict__ wout, short* __restrict__ xb,
    short* __restrict__ wqkvT, short* __restrict__ woutT)
{
  __shared__ float tile[32][33];
  const int bid = blockIdx.x, tid = threadIdx.x;
  if (bid < 512){
    int base = bid*2048 + tid;          // 2048 float4 per block
    #pragma unroll
    for (int it=0; it<8; it++){
      int i = base + it*256;
      f32x4 v = ((const f32x4*)x)[i];
      short4_t s;
      s[0]=f2bf(v[0]); s[1]=f2bf(v[1]); s[2]=f2bf(v[2]); s[3]=f2bf(v[3]);
      ((short4_t*)xb)[i] = s;
    }
    return;
  }
  const float* w; short* wT; int N, idx;
  if (bid < 3584){ w = wqkv; wT = wqkvT; N = 3072; idx = bid - 512;  }
  else           { w = wout; wT = woutT; N = 1024; idx = bid - 3584; }
  const int K = 1024;
  int bn = (idx % (N >> 5)) * 32, bk = (idx / (N >> 5)) * 32;
  int tx = tid & 31, ty = tid >> 5;
  #pragma unroll
  for (int r=ty; r<32; r+=8) tile[r][tx] = w[(size_t)(bk+r)*N + bn + tx];
  __syncthreads();
  #pragma unroll
  for (int r=ty; r<32; r+=8) wT[(size_t)(bn+r)*K + bk + tx] = f2bf(tile[tx][r]);
}

// ---------------- 128x128 bf16 GEMM: C = A[M][K] * Bt[N][K]^T ----------------
template<int MODE>
__global__ __launch_bounds__(256) void gemm128_kernel(
    const short* __restrict__ A, const short* __restrict__ Bt,
    float* __restrict__ Cf, short* __restrict__ qb_, short* __restrict__ kb_,
    short* __restrict__ vtb, int M, int N, int K)
{
  __shared__ short a_lds[128*64];
  __shared__ short b_lds[128*64];
  const int tid = threadIdx.x;
  const int lane = tid & 63;
  const int l15 = lane & 15, lg = lane >> 4;
  const int w  = tid >> 6;
  const int wr = w >> 1, wc = w & 1;
  const int m0 = blockIdx.x * 128, n0 = blockIdx.y * 128;

  f32x4 acc[4][4];
  #pragma unroll
  for (int i=0;i<4;i++)
    #pragma unroll
    for (int j=0;j<4;j++) acc[i][j] = (f32x4){0.f,0.f,0.f,0.f};

  for (int kt = 0; kt < K; kt += 64){
    __syncthreads();
    #pragma unroll
    for (int i=0;i<4;i++){
      int u = i*256 + tid;
      int row = u >> 3, cu = u & 7;
      int kl = ((cu ^ (row & 7)) << 3);
      GLOAD_LDS16(A + (size_t)(m0+row)*K + kt + kl, a_lds + (size_t)(i*256 + (tid & ~63))*8);
    }
    #pragma unroll
    for (int i=0;i<4;i++){
      int u = i*256 + tid;
      int row = u >> 3, cu = u & 7;
      int kl = ((cu ^ (row & 7)) << 3);
      GLOAD_LDS16(Bt + (size_t)(n0+row)*K + kt + kl, b_lds + (size_t)(i*256 + (tid & ~63))*8);
    }
    asm volatile("s_waitcnt vmcnt(0)" ::: "memory");
    __syncthreads();

    #pragma unroll
    for (int kk=0;kk<2;kk++){
      short8 af[4], bfr[4];
      #pragma unroll
      for (int mi=0;mi<4;mi++){
        int row = wr*64 + mi*16 + l15;
        int uu = ((kk*4 + lg) ^ (row & 7));
        af[mi] = *(const short8*)&a_lds[row*64 + uu*8];
      }
      #pragma unroll
      for (int ni=0;ni<4;ni++){
        int row = wc*64 + ni*16 + l15;
        int uu = ((kk*4 + lg) ^ (row & 7));
        bfr[ni] = *(const short8*)&b_lds[row*64 + uu*8];
      }
      #pragma unroll
      for (int mi=0;mi<4;mi++)
        #pragma unroll
        for (int ni=0;ni<4;ni++)
          acc[mi][ni] = __builtin_amdgcn_mfma_f32_16x16x32_bf16(af[mi], bfr[ni], acc[mi][ni], 0,0,0);
    }
  }

  // epilogue: D layout col = lane&15, row = (lane>>4)*4 + r  [verified m89/m91]
  #pragma unroll
  for (int mi=0;mi<4;mi++){
    #pragma unroll
    for (int ni=0;ni<4;ni++){
      int col = n0 + wc*64 + ni*16 + l15;
      #pragma unroll
      for (int r=0;r<4;r++){
        int rowg = m0 + wr*64 + mi*16 + lg*4 + r;
        float v = acc[mi][ni][r];
        if (MODE == 0){
          Cf[(size_t)rowg*N + col] = v;
        } else {
          int three = col >> 10, hh = (col >> 6) & 15, e = col & 63;
          int bb = rowg >> 11, t = rowg & 2047;
          int bh = bb*16 + hh;
          // Q pre-scale: 1/sqrt(64) * log2(e)  (softmax computed in base 2)
          if (three == 0)      qb_[((size_t)bh*2048 + t)*64 + e] = f2bf(v * (0.125f*1.44269504f));
          else if (three == 1) kb_[((size_t)bh*2048 + t)*64 + e] = f2bf(v);
          else                 vtb[((size_t)bh*64 + e)*2048 + t] = f2bf(v);   // V^T direct
        }
      }
    }
  }
}

// ---------------- causal flash attention: 32x32 MFMA, split-KV, in-block combine ----------------
// 512 threads = 8 waves: wg = w&3 owns 32 q-rows (QBLK=128); g = w>>2 owns kv half
// [g*64, g*64+64) of every 128-wide KV tile with private (m,l,O). End: exact flash
// combine through dead K/V LDS. Doubles wave count (4096) at same HBM traffic.
__global__ __launch_bounds__(512) void attn_kernel(
    const short* __restrict__ q, const short* __restrict__ kbuf,
    const short* __restrict__ vt, short* __restrict__ ob)
{
  __shared__ short sm[2*128*64 + 2*64*128];   // 64 KiB: K dbuf then V dbuf
  short* k_lds = sm;                          // [2][128*64]  [kv][k]
  short* v_lds = sm + 2*128*64;               // [2][64*128]  [d][kv] (V^T)

  const int tid = threadIdx.x, lane = tid & 63, w = tid >> 6;   // 0..7
  const int wg = w & 3, g = w >> 2;
  const int l31 = lane & 31, hi = lane >> 5;
  const int qi = blockIdx.x >> 5;
  const int qb = (qi < 8) ? (15 - qi) : (qi - 8);   // paired blocks sum to 17 tiles
  const int bh = blockIdx.x & 31;
  const int q0 = qb * 128;

  const short* qg = q + ((size_t)bh*2048 + q0 + wg*32 + l31)*64 + hi*8;
  short8 qf[4];
  #pragma unroll
  for (int kk=0;kk<4;kk++) qf[kk] = *(const short8*)(qg + kk*16);

  f32x16 o_acc[2];
  #pragma unroll
  for (int oc=0;oc<2;oc++)
    #pragma unroll
    for (int r=0;r<16;r++) o_acc[oc][r] = 0.f;
  float mreg = -1e30f, lreg = 0.f;    // per-lane: q = l31 (hi halves duplicate)

  // group-local LDS read offsets (bytes). K row = g*64 + ct*32 + l31 (128B rows);
  // V row = oc*32 + l31 (256B rows), in-row kv-half offset g*128. Swizzle commutes
  // with the +g offsets (XOR touches only low 3 unit bits).
  const int sw = l31 & 7;
  int kro[4], vro[4];
  #pragma unroll
  for (int kk=0;kk<4;kk++) kro[kk] = g*8192 + l31*128 + (((kk*2+hi)^sw) << 4);
  #pragma unroll
  for (int ks=0;ks<4;ks++) vro[ks] = g*128  + l31*256 + (((ks*2+hi)^sw) << 4);

  // staging (512 thr): K 2 issues x 64 rows; V 2 issues x 32 rows; src pre-swizzled
  const int xk = ((tid & 7) ^ ((tid >> 3) & 7)) * 8;
  const int xv = ((tid & 15) ^ ((tid >> 4) & 7)) * 8;
  const short* kp = kbuf + (size_t)bh*2048*64 + (size_t)(tid >> 3)*64 + xk;    // +8192/tile
  const short* vp = vt   + (size_t)bh*64*2048 + (size_t)(tid >> 4)*2048 + xv;  // +128/tile
  const int dst = (tid & ~63)*8;   // wave-uniform LDS dest base (shorts)

  const int n = qb + 1;
  #pragma unroll
  for (int i=0;i<2;i++) GLOAD_LDS16(kp + i*4096,  k_lds + i*4096 + dst);
  #pragma unroll
  for (int i=0;i<2;i++) GLOAD_LDS16(vp + i*65536, v_lds + i*4096 + dst);
  kp += 8192; vp += 128;

  for (int s = 0; s < n; s++){
    const int cur = s & 1;
    if (s + 1 < n){
      #pragma unroll
      for (int i=0;i<2;i++) GLOAD_LDS16(kp + i*4096,  k_lds + (cur^1)*8192 + i*4096 + dst);
      #pragma unroll
      for (int i=0;i<2;i++) GLOAD_LDS16(vp + i*65536, v_lds + (cur^1)*8192 + i*4096 + dst);
      kp += 8192; vp += 128;
      asm volatile("s_waitcnt vmcnt(4)" ::: "memory");  // tile s landed; s+1 in flight
    } else {
      asm volatile("s_waitcnt vmcnt(0)" ::: "memory");
    }
    __builtin_amdgcn_s_barrier();

    const char* klp = (const char*)(k_lds + cur*8192);
    const char* vlp = (const char*)(v_lds + cur*8192);

    // QK^T (group half): sacc[ct][r] = S^T[kv = s*128 + g*64 + ct*32 + crow(r,hi)][q=l31]
    f32x16 sacc[2];
    #pragma unroll
    for (int ct=0;ct<2;ct++)
      #pragma unroll
      for (int r=0;r<16;r++) sacc[ct][r] = 0.f;
    __builtin_amdgcn_s_setprio(1);
    #pragma unroll
    for (int kk=0;kk<4;kk++){
      #pragma unroll
      for (int ct=0;ct<2;ct++){
        short8 kf = *(const short8*)(klp + kro[kk] + ct*4096);
        sacc[ct] = __builtin_amdgcn_mfma_f32_32x32x16_bf16(kf, qf[kk], sacc[ct], 0,0,0);
      }
    }
    __builtin_amdgcn_s_setprio(0);

    if (s == qb){   // diagonal tile: mask kv_local > q_local
      const int qloc = wg*32 + l31 - 4*hi;
      #pragma unroll
      for (int ct=0;ct<2;ct++)
        #pragma unroll
        for (int r=0;r<16;r++)
          if (g*64 + ct*32 + (r&3) + 8*(r>>2) > qloc) sacc[ct][r] = -1e30f;
    }

    float pmax = sacc[0][0];
    #pragma unroll
    for (int ct=0;ct<2;ct++)
      #pragma unroll
      for (int r=0;r<16;r++) pmax = fmaxf(pmax, sacc[ct][r]);
    pmax = fmaxf(pmax, __shfl_xor(pmax, 32));

    if (!__all(pmax - mreg <= 8.0f)){       // T13 defer-rescale
      float mnew = fmaxf(mreg, pmax);
      float alpha = exp2_fast(mreg - mnew);
      mreg = mnew;
      lreg *= alpha;
      float aRow[16];
      #pragma unroll
      for (int r=0;r<16;r++) aRow[r] = __shfl(alpha, (r&3) + 8*(r>>2) + 4*hi);
      #pragma unroll
      for (int oc=0;oc<2;oc++)
        #pragma unroll
        for (int r=0;r<16;r++) o_acc[oc][r] *= aRow[r];
    }

    float sum = 0.f;
    #pragma unroll
    for (int ct=0;ct<2;ct++){
      float pv[16];
      #pragma unroll
      for (int r=0;r<16;r++){ pv[r] = exp2_fast(sacc[ct][r] - mreg); sum += pv[r]; }
      unsigned pk[8];
      #pragma unroll
      for (int t=0;t<8;t++)
        asm("v_cvt_pk_bf16_f32 %0, %1, %2" : "=v"(pk[t]) : "v"(pv[2*t]), "v"(pv[2*t+1]));
      #pragma unroll
      for (int kss=0;kss<2;kss++){        // ks = 2*ct + kss (group-local, 4 of them)
        const int W = 4*kss;
        unsigned x0 = pk[W],   x2 = pk[W+2];
        unsigned x1 = pk[W+1], x3 = pk[W+3];
        asm("v_permlane32_swap_b32 %0, %1" : "+v"(x0), "+v"(x2));
        asm("v_permlane32_swap_b32 %0, %1" : "+v"(x1), "+v"(x3));
        uint4 pau = {x0, x1, x2, x3};
        short8 pa = __builtin_bit_cast(short8, pau);
        __builtin_amdgcn_s_setprio(1);
        #pragma unroll
        for (int oc=0;oc<2;oc++){
          short8 vf = *(const short8*)(vlp + vro[2*ct+kss] + oc*8192);
          o_acc[oc] = __builtin_amdgcn_mfma_f32_32x32x16_bf16(pa, vf, o_acc[oc], 0,0,0);
        }
        __builtin_amdgcn_s_setprio(0);
      }
    }
    sum += __shfl_xor(sum, 32);
    lreg += sum;

    __builtin_amdgcn_s_barrier();   // all reads of buf[cur] done before overwrite
  }

  // ---- cross-group combine (exact): O = s0*O0 + s1*O1, l = s0*l0 + s1*l1 ----
  // K/V LDS is dead now; reuse as f32 scratch. Per wg: [m(64)][l(64)][o 32x64] = 2176 f.
  float* cmb = (float*)sm;
  if (g == 1){
    float* bse = cmb + wg*2176;
    bse[lane] = mreg;
    bse[64 + lane] = lreg;
    #pragma unroll
    for (int oc=0;oc<2;oc++)
      #pragma unroll
      for (int r=0;r<16;r++) bse[(2 + oc*16 + r)*64 + lane] = o_acc[oc][r];
  }
  __syncthreads();
  if (g == 0){
    float* bse = cmb + wg*2176;
    float m1 = bse[lane], l1 = bse[64 + lane];
    float mN = fmaxf(mreg, m1);
    float s0 = exp2_fast(mreg - mN), s1 = exp2_fast(m1 - mN);
    float lt = s0*lreg + s1*l1;
    float s0R[16], s1R[16];
    #pragma unroll
    for (int r=0;r<16;r++){
      int src = (r&3) + 8*(r>>2) + 4*hi;
      s0R[r] = __shfl(s0, src); s1R[r] = __shfl(s1, src);
    }
    #pragma unroll
    for (int oc=0;oc<2;oc++)
      #pragma unroll
      for (int r=0;r<16;r++)
        o_acc[oc][r] = s0R[r]*o_acc[oc][r] + s1R[r]*bse[(2 + oc*16 + r)*64 + lane];

    const int bb = bh >> 4, hh = bh & 15;
    #pragma unroll
    for (int r=0;r<16;r++){
      float lf = __shfl(lt, (r&3) + 8*(r>>2) + 4*hi);
      float inv = 1.0f / lf;
      int t = q0 + wg*32 + (r&3) + 8*(r>>2) + 4*hi;
      size_t base = ((size_t)(bb*2048 + t))*1024 + (size_t)hh*64 + l31;
      ob[base]      = f2bf(o_acc[0][r] * inv);
      ob[base + 32] = f2bf(o_acc[1][r] * inv);
    }
  }
}

extern "C" void kernel_launch(void* const* d_in, const int* in_sizes, int n_in,
                              void* d_out, int out_size, void* d_ws, size_t ws_size,
                              hipStream_t stream) {
  const float* x     = (const float*)d_in[0];   // [2,2048,1024]
  const float* w_qkv = (const float*)d_in[1];   // [1024,3072]
  const float* w_out = (const float*)d_in[2];   // [1024,1024]
  float* out = (float*)d_out;                   // [2,2048,1024] fp32

  char* ws = (char*)d_ws;
  short* xb    = (short*)(ws);                    // 8 MB  [4096][1024] bf16
  short* wqkvT = (short*)(ws + (8u  << 20));      // 6 MB  [3072][1024] bf16
  short* woutT = (short*)(ws + (14u << 20));      // 2 MB  [1024][1024] bf16
  short* qbuf  = (short*)(ws + (16u << 20));      // 8 MB  [32][2048][64] bf16 (prescaled)
  short* kbuf  = (short*)(ws + (24u << 20));      // 8 MB  [32][2048][64] bf16
  short* vtbuf = (short*)(ws + (32u << 20));      // 8 MB  [32][64][2048] bf16 (V^T)
  short* obuf  = (short*)(ws + (40u << 20));      // 8 MB  [4096][1024] bf16

  prep_kernel<<<4608, 256, 0, stream>>>(x, w_qkv, w_out, xb, wqkvT, woutT);
  gemm128_kernel<1><<<dim3(32,24), 256, 0, stream>>>(xb, wqkvT, nullptr,
                                                     qbuf, kbuf, vtbuf, 4096, 3072, 1024);
  attn_kernel<<<dim3(512), 512, 0, stream>>>(qbuf, kbuf, vtbuf, obuf);
  gemm128_kernel<0><<<dim3(32,8), 256, 0, stream>>>(obuf, woutT, out,
                                                    nullptr, nullptr, nullptr, 4096, 1024, 1024);
}